// Round 9
// baseline (891.458 us; speedup 1.0000x reference)
//
#include <hip/hip_runtime.h>
#include <hip/hip_cooperative_groups.h>
#include <hip/hip_bf16.h>

namespace cg = cooperative_groups;

#define NN 100000
#define NE 800000
#define DIM 96
#define NEG_SLOPE 0.01f
#define SCANB ((NN + 255) / 256)        // 391 virtual scan blocks
#define GEMM_TILES ((NN + 63) / 64)     // 1563 64-row tiles

typedef short bf16x8 __attribute__((ext_vector_type(8)));
typedef float f32x4  __attribute__((ext_vector_type(4)));

__device__ __forceinline__ unsigned short f32_to_bf16_rne(float f) {
    unsigned int u = __float_as_uint(f);
    unsigned int r = (u + 0x7FFFu + ((u >> 16) & 1u)) >> 16;
    return (unsigned short)r;
}
__device__ __forceinline__ float bf16lo_to_f32(unsigned int u) { return __uint_as_float(u << 16); }
__device__ __forceinline__ float bf16hi_to_f32(unsigned int u) { return __uint_as_float(u & 0xFFFF0000u); }

struct FusedArgs {
    const int* src; const int* dst;
    const float* x; const float* W1; const float* a1; const float* W2; const float* a2;
    float* out;
    int* deg; int* row_ptr; int* cursor; int* dst_perm; int* blocksum; int* blockoff;
    unsigned short* Wt1; unsigned short* Wt2;
    unsigned short* h1; unsigned short* h2;
    float* ssrc; float* sdst;
};

// ---- GEMM phase: H[N,96](bf16) = A @ W, + fused dots (ssrc/sdst). ----
// 4 waves/block, wave = 16 rows; B-frags streamed per n-tile (each used once).
template <bool A_BF16>
__device__ __forceinline__ void gemm_phase(const void* __restrict__ A_,
                                           const unsigned short* __restrict__ Wt,
                                           const float* __restrict__ avec,
                                           unsigned short* __restrict__ Hout,
                                           float* __restrict__ ssrc, float* __restrict__ sdst) {
    const int wave = threadIdx.x >> 6;
    const int lane = threadIdx.x & 63;
    const int quad = lane >> 4;
    const int l16  = lane & 15;

    float as_[6], ad_[6];
#pragma unroll
    for (int nt = 0; nt < 6; nt++) {
        as_[nt] = avec[nt * 16 + l16];
        ad_[nt] = avec[96 + nt * 16 + l16];
    }

    for (int tb = blockIdx.x; tb < GEMM_TILES; tb += gridDim.x) {
        const int R0 = tb * 64 + wave * 16;
        int arow = R0 + l16;
        if (arow >= NN) arow = NN - 1;               // clamp; stores guarded

        bf16x8 afr[3];
        if (A_BF16) {
            const unsigned short* ap = (const unsigned short*)A_ + (size_t)arow * DIM;
#pragma unroll
            for (int kc = 0; kc < 3; kc++) afr[kc] = *(const bf16x8*)(ap + kc * 32 + quad * 8);
        } else {
            const float* ap = (const float*)A_ + (size_t)arow * DIM;
#pragma unroll
            for (int kc = 0; kc < 3; kc++) {
                float4 lo = *(const float4*)(ap + kc * 32 + quad * 8);
                float4 hi = *(const float4*)(ap + kc * 32 + quad * 8 + 4);
                union { bf16x8 v; unsigned short u[8]; } t;
                t.u[0] = f32_to_bf16_rne(lo.x); t.u[1] = f32_to_bf16_rne(lo.y);
                t.u[2] = f32_to_bf16_rne(lo.z); t.u[3] = f32_to_bf16_rne(lo.w);
                t.u[4] = f32_to_bf16_rne(hi.x); t.u[5] = f32_to_bf16_rne(hi.y);
                t.u[6] = f32_to_bf16_rne(hi.z); t.u[7] = f32_to_bf16_rne(hi.w);
                afr[kc] = t.v;
            }
        }

        f32x4 acc[6];
#pragma unroll
        for (int nt = 0; nt < 6; nt++) acc[nt] = (f32x4){0.f, 0.f, 0.f, 0.f};
#pragma unroll
        for (int nt = 0; nt < 6; nt++) {
            const unsigned short* wrow = Wt + (size_t)(nt * 16 + l16) * DIM;
            bf16x8 b0 = *(const bf16x8*)(wrow + quad * 8);
            bf16x8 b1 = *(const bf16x8*)(wrow + 32 + quad * 8);
            bf16x8 b2 = *(const bf16x8*)(wrow + 64 + quad * 8);
            acc[nt] = __builtin_amdgcn_mfma_f32_16x16x32_bf16(afr[0], b0, acc[nt], 0, 0, 0);
            acc[nt] = __builtin_amdgcn_mfma_f32_16x16x32_bf16(afr[1], b1, acc[nt], 0, 0, 0);
            acc[nt] = __builtin_amdgcn_mfma_f32_16x16x32_bf16(afr[2], b2, acc[nt], 0, 0, 0);
        }

        // fused dots
        float ps[4], pd[4];
#pragma unroll
        for (int r = 0; r < 4; r++) {
            float s = 0.f, d = 0.f;
#pragma unroll
            for (int nt = 0; nt < 6; nt++) {
                s = fmaf(acc[nt][r], as_[nt], s);
                d = fmaf(acc[nt][r], ad_[nt], d);
            }
            ps[r] = s; pd[r] = d;
        }
#pragma unroll
        for (int m = 1; m < 16; m <<= 1) {
#pragma unroll
            for (int r = 0; r < 4; r++) {
                ps[r] += __shfl_xor(ps[r], m);
                pd[r] += __shfl_xor(pd[r], m);
            }
        }
        {
            float psel = (l16 == 0) ? ps[0] : (l16 == 1) ? ps[1] : (l16 == 2) ? ps[2] : ps[3];
            float dsel = (l16 == 8) ? pd[0] : (l16 == 9) ? pd[1] : (l16 == 10) ? pd[2] : pd[3];
            int rs = R0 + quad * 4 + l16;
            int rd = R0 + quad * 4 + (l16 - 8);
            if (l16 < 4 && rs < NN) ssrc[rs] = psel;
            if (l16 >= 8 && l16 < 12 && rd < NN) sdst[rd] = dsel;
        }

        // store H bf16
#pragma unroll
        for (int r = 0; r < 4; r++) {
            int orow = R0 + quad * 4 + r;
            if (orow < NN) {
                unsigned short* hrow = Hout + (size_t)orow * DIM;
#pragma unroll
                for (int nt = 0; nt < 6; nt++) hrow[nt * 16 + l16] = f32_to_bf16_rne(acc[nt][r]);
            }
        }
    }
}

// ---- agg phase: out[n] = sum(w*h[dst]) / sum(w); batch-8, lanes 0..7 own exp. ----
template <bool RELU, bool OUT_BF16>
__device__ __forceinline__ void agg_phase(const unsigned short* __restrict__ h,
                                          const float* __restrict__ ssrc,
                                          const float* __restrict__ sdst,
                                          const int* __restrict__ row_ptr,
                                          const int* __restrict__ dst_perm,
                                          void* __restrict__ out) {
    const int lane = threadIdx.x & 63;
    const int gw   = blockIdx.x * 4 + (threadIdx.x >> 6);
    const int nw   = gridDim.x * 4;
    const bool act = lane < 48;

    for (int node = gw; node < NN; node += nw) {
        int start = row_ptr[node];
        int end   = row_ptr[node + 1];
        float ss  = ssrc[node];
        float acc0 = 0.f, acc1 = 0.f, wsum = 0.f;

        for (int p = start; p < end; p += 8) {
            const int cnt = min(8, end - p);
            int d[8];
#pragma unroll
            for (int i = 0; i < 8; i++) {
                int idx = p + i;
                d[i] = dst_perm[(idx < end) ? idx : p];
            }
            float wl = 0.f;
            if (lane < cnt) {
                float s  = ss + sdst[d[lane]];
                float lr = s > 0.f ? s : NEG_SLOPE * s;
                wl = __expf(-lr);
            }
            unsigned int u[8];
            if (act) {
#pragma unroll
                for (int i = 0; i < 8; i++)
                    u[i] = ((const unsigned int*)(h + (size_t)d[i] * DIM))[lane];
            }
#pragma unroll
            for (int i = 0; i < 8; i++) {
                float w = __shfl(wl, i);
                wsum += w;
                if (act) {
                    acc0 = fmaf(w, bf16lo_to_f32(u[i]), acc0);
                    acc1 = fmaf(w, bf16hi_to_f32(u[i]), acc1);
                }
            }
        }

        float inv = 1.f / wsum;
        float r0 = acc0 * inv;
        float r1 = acc1 * inv;
        if (RELU) { r0 = fmaxf(r0, 0.f); r1 = fmaxf(r1, 0.f); }
        if (act) {
            if (OUT_BF16) {
                unsigned int pk = (unsigned int)f32_to_bf16_rne(r0) | ((unsigned int)f32_to_bf16_rne(r1) << 16);
                ((unsigned int*)out)[(size_t)node * 48 + lane] = pk;
            } else {
                ((float2*)out)[(size_t)node * 48 + lane] = make_float2(r0, r1);
            }
        }
    }
}

// ---- the whole pipeline, one cooperative kernel ----
__global__ __launch_bounds__(256, 4) void fused_kernel(FusedArgs A) {
    cg::grid_group grid = cg::this_grid();
    const int tid  = blockIdx.x * 256 + threadIdx.x;
    const int nthr = gridDim.x * 256;
    const int t    = threadIdx.x;
    __shared__ int sA[256];
    __shared__ int sB[256];

    // P0: zero deg + W converts (transpose to [n][k] bf16)
    for (int i = tid; i < NN; i += nthr) A.deg[i] = 0;
    for (int i = tid; i < 2 * DIM * DIM; i += nthr) {
        if (i < DIM * DIM) {
            int n = i / DIM, k = i % DIM;
            A.Wt1[n * DIM + k] = f32_to_bf16_rne(A.W1[k * DIM + n]);
        } else {
            int j = i - DIM * DIM;
            int n = j / DIM, k = j % DIM;
            A.Wt2[n * DIM + k] = f32_to_bf16_rne(A.W2[k * DIM + n]);
        }
    }
    grid.sync();

    // P1: histogram + layer-1 GEMM(+dots) — independent work, one phase
    for (int e = tid; e < NE; e += nthr) atomicAdd(&A.deg[A.src[e]], 1);
    gemm_phase<false>(A.x, A.Wt1, A.a1, A.h1, A.ssrc, A.sdst);
    grid.sync();

    // P2: per-virtual-block partial sums of deg
    for (int vb = blockIdx.x; vb < SCANB; vb += gridDim.x) {
        int idx = vb * 256 + t;
        int v = (idx < NN) ? A.deg[idx] : 0;
        sA[t] = v;
        __syncthreads();
        for (int off = 128; off > 0; off >>= 1) {
            if (t < off) sA[t] += sA[t + off];
            __syncthreads();
        }
        if (t == 0) A.blocksum[vb] = sA[0];
        __syncthreads();
    }
    grid.sync();

    // P3: block 0 scans the 391 partials (two 256-wide Hillis-Steele scans)
    if (blockIdx.x == 0) {
        int v1 = (t < SCANB) ? A.blocksum[t] : 0;
        int v2 = (256 + t < SCANB) ? A.blocksum[256 + t] : 0;
        sA[t] = v1; sB[t] = v2;
        __syncthreads();
        for (int off = 1; off < 256; off <<= 1) {
            int x1 = (t >= off) ? sA[t - off] : 0;
            int x2 = (t >= off) ? sB[t - off] : 0;
            __syncthreads();
            sA[t] += x1; sB[t] += x2;
            __syncthreads();
        }
        int totalA = sA[255];
        A.blockoff[t] = sA[t] - v1;
        if (256 + t < SCANB) A.blockoff[256 + t] = totalA + sB[t] - v2;
    }
    grid.sync();

    // P4: row_ptr + cursor (block-local scan + block offset)
    for (int vb = blockIdx.x; vb < SCANB; vb += gridDim.x) {
        int idx = vb * 256 + t;
        int v = (idx < NN) ? A.deg[idx] : 0;
        sA[t] = v;
        __syncthreads();
        for (int off = 1; off < 256; off <<= 1) {
            int x = (t >= off) ? sA[t - off] : 0;
            __syncthreads();
            sA[t] += x;
            __syncthreads();
        }
        if (idx < NN) {
            int r = A.blockoff[vb] + sA[t] - v;
            A.row_ptr[idx] = r;
            A.cursor[idx]  = r;
        }
        __syncthreads();
    }
    if (tid == 0) A.row_ptr[NN] = NE;
    grid.sync();

    // P5: fill dst_perm (CSR order)
    for (int e = tid; e < NE; e += nthr) {
        int s = A.src[e];
        int pos = atomicAdd(&A.cursor[s], 1);
        A.dst_perm[pos] = A.dst[e];
    }
    grid.sync();

    // P6: layer-1 aggregation -> h2 (bf16)
    agg_phase<false, true>(A.h1, A.ssrc, A.sdst, A.row_ptr, A.dst_perm, A.h2);
    grid.sync();

    // P7: layer-2 GEMM(+dots) -> h1, ssrc, sdst
    gemm_phase<true>(A.h2, A.Wt2, A.a2, A.h1, A.ssrc, A.sdst);
    grid.sync();

    // P8: layer-2 aggregation + relu -> out (fp32)
    agg_phase<true, false>(A.h1, A.ssrc, A.sdst, A.row_ptr, A.dst_perm, A.out);
}

// ---------------- launch ----------------

extern "C" void kernel_launch(void* const* d_in, const int* in_sizes, int n_in,
                              void* d_out, int out_size, void* d_ws, size_t ws_size,
                              hipStream_t stream) {
    (void)in_sizes; (void)n_in; (void)out_size; (void)ws_size;
    const int*   edge_index = (const int*)d_in[0];
    const float* x  = (const float*)d_in[1];
    const float* W1 = (const float*)d_in[2];
    const float* a1 = (const float*)d_in[3];
    const float* W2 = (const float*)d_in[4];
    const float* a2 = (const float*)d_in[5];

    char* ws = (char*)d_ws;
    size_t off = 0;
    auto alloc = [&](size_t bytes) -> void* {
        void* p = ws + off;
        off += (bytes + 255) & ~(size_t)255;
        return p;
    };

    FusedArgs fa;
    fa.src = edge_index;
    fa.dst = edge_index + NE;
    fa.x = x; fa.W1 = W1; fa.a1 = a1; fa.W2 = W2; fa.a2 = a2;
    fa.out = (float*)d_out;
    fa.h1       = (unsigned short*)alloc((size_t)NN * DIM * 2);
    fa.h2       = (unsigned short*)alloc((size_t)NN * DIM * 2);
    fa.ssrc     = (float*)alloc((size_t)NN * 4);
    fa.sdst     = (float*)alloc((size_t)NN * 4);
    fa.deg      = (int*)alloc((size_t)NN * 4);
    fa.row_ptr  = (int*)alloc((size_t)(NN + 1) * 4);
    fa.cursor   = (int*)alloc((size_t)NN * 4);
    fa.dst_perm = (int*)alloc((size_t)NE * 4);
    fa.blocksum = (int*)alloc((size_t)512 * 4);
    fa.blockoff = (int*)alloc((size_t)512 * 4);
    fa.Wt1      = (unsigned short*)alloc((size_t)DIM * DIM * 2);
    fa.Wt2      = (unsigned short*)alloc((size_t)DIM * DIM * 2);

    int maxB = 0;
    hipOccupancyMaxActiveBlocksPerMultiprocessor(&maxB, fused_kernel, 256, 0);
    if (maxB < 1) maxB = 1;
    int grid = maxB * 256;
    if (grid > 1024) grid = 1024;

    void* kargs[] = { (void*)&fa };
    hipLaunchCooperativeKernel((void*)fused_kernel, dim3(grid), dim3(256), kargs, 0, stream);
}

// Round 10
// 306.832 us; speedup vs baseline: 2.9054x; 2.9054x over previous
//
#include <hip/hip_runtime.h>
#include <hip/hip_bf16.h>

#define NN 100000
#define NE 800000
#define DIM 96
#define NEG_SLOPE 0.01f
#define SCAN_BLOCKS ((NN + 255) / 256)             // 391
#define EDGE_BLOCKS ((NE + 255) / 256)             // 3125
#define CONV_BLOCKS ((2 * DIM * DIM + 255) / 256)  // 72
#define GEMM_TILES ((NN + 63) / 64)                // 1563

typedef short bf16x8 __attribute__((ext_vector_type(8)));
typedef float f32x4  __attribute__((ext_vector_type(4)));

__device__ __forceinline__ unsigned short f32_to_bf16_rne(float f) {
    unsigned int u = __float_as_uint(f);
    unsigned int r = (u + 0x7FFFu + ((u >> 16) & 1u)) >> 16;
    return (unsigned short)r;
}
__device__ __forceinline__ float bf16lo_to_f32(unsigned int u) { return __uint_as_float(u << 16); }
__device__ __forceinline__ float bf16hi_to_f32(unsigned int u) { return __uint_as_float(u & 0xFFFF0000u); }

// ---------------- CSR build + W convert ----------------

__global__ __launch_bounds__(256) void hist_conv_kernel(const int* __restrict__ src, int* __restrict__ deg,
                                                        const float* __restrict__ W1, unsigned short* __restrict__ Wt1,
                                                        const float* __restrict__ W2, unsigned short* __restrict__ Wt2) {
    if (blockIdx.x < EDGE_BLOCKS) {
        int e = blockIdx.x * 256 + threadIdx.x;
        if (e < NE) atomicAdd(&deg[src[e]], 1);
    } else {
        int idx = (blockIdx.x - EDGE_BLOCKS) * 256 + threadIdx.x;
        if (idx < DIM * DIM) {
            int n = idx / DIM, k = idx % DIM;
            Wt1[n * DIM + k] = f32_to_bf16_rne(W1[k * DIM + n]);
        } else if (idx < 2 * DIM * DIM) {
            int j = idx - DIM * DIM;
            int n = j / DIM, k = j % DIM;
            Wt2[n * DIM + k] = f32_to_bf16_rne(W2[k * DIM + n]);
        }
    }
}

__global__ __launch_bounds__(256) void partial_kernel(const int* __restrict__ deg, int* __restrict__ blocksum) {
    __shared__ int lds[4];
    int idx = blockIdx.x * 256 + threadIdx.x;
    int v = (idx < NN) ? deg[idx] : 0;
    for (int off = 32; off > 0; off >>= 1) v += __shfl_down(v, off);
    int wave = threadIdx.x >> 6;
    int lane = threadIdx.x & 63;
    if (lane == 0) lds[wave] = v;
    __syncthreads();
    if (threadIdx.x == 0) blocksum[blockIdx.x] = lds[0] + lds[1] + lds[2] + lds[3];
}

// block vb: computes its own exclusive offset (sum of preceding blocksums), then
// block-local scan of deg -> row_ptr/cursor. Merges old scan_partials+rowptr.
__global__ __launch_bounds__(256) void scan_rowptr_kernel(const int* __restrict__ deg,
                                                          const int* __restrict__ blocksum,
                                                          int* __restrict__ row_ptr, int* __restrict__ cursor) {
    __shared__ int sA[256];
    const int t  = threadIdx.x;
    const int vb = blockIdx.x;

    // exclusive block offset
    int po = 0;
    for (int j = t; j < vb; j += 256) po += blocksum[j];
    sA[t] = po;
    __syncthreads();
    for (int off = 128; off > 0; off >>= 1) {
        if (t < off) sA[t] += sA[t + off];
        __syncthreads();
    }
    const int blockoff = sA[0];
    __syncthreads();

    // block-local inclusive scan of deg
    int idx = vb * 256 + t;
    int v = (idx < NN) ? deg[idx] : 0;
    sA[t] = v;
    __syncthreads();
    for (int off = 1; off < 256; off <<= 1) {
        int x = (t >= off) ? sA[t - off] : 0;
        __syncthreads();
        sA[t] += x;
        __syncthreads();
    }
    if (idx < NN) {
        int r = blockoff + sA[t] - v;   // exclusive prefix
        row_ptr[idx] = r;
        cursor[idx]  = r;
    }
    if (idx == 0) row_ptr[NN] = NE;
}

// ---------------- GEMM tile (device): H[64 rows](bf16) = A @ W, + fused dots ----------------

template <bool A_BF16>
__device__ __forceinline__ void gemm_tile(int tb,
                                          const void* __restrict__ A_,
                                          const unsigned short* __restrict__ Wt,
                                          const float* __restrict__ avec,
                                          unsigned short* __restrict__ Hout,
                                          float* __restrict__ ssrc, float* __restrict__ sdst) {
    const int wave = threadIdx.x >> 6;
    const int lane = threadIdx.x & 63;
    const int quad = lane >> 4;
    const int l16  = lane & 15;
    const int R0   = tb * 64 + wave * 16;

    bf16x8 bfr[6][3];
#pragma unroll
    for (int nt = 0; nt < 6; nt++) {
        const unsigned short* wrow = Wt + (size_t)(nt * 16 + l16) * DIM;
#pragma unroll
        for (int kc = 0; kc < 3; kc++) bfr[nt][kc] = *(const bf16x8*)(wrow + kc * 32 + quad * 8);
    }

    int arow = R0 + l16;
    if (arow >= NN) arow = NN - 1;               // clamp; stores guarded
    bf16x8 afr[3];
    if (A_BF16) {
        const unsigned short* ap = (const unsigned short*)A_ + (size_t)arow * DIM;
#pragma unroll
        for (int kc = 0; kc < 3; kc++) afr[kc] = *(const bf16x8*)(ap + kc * 32 + quad * 8);
    } else {
        const float* ap = (const float*)A_ + (size_t)arow * DIM;
#pragma unroll
        for (int kc = 0; kc < 3; kc++) {
            float4 lo = *(const float4*)(ap + kc * 32 + quad * 8);
            float4 hi = *(const float4*)(ap + kc * 32 + quad * 8 + 4);
            union { bf16x8 v; unsigned short u[8]; } t;
            t.u[0] = f32_to_bf16_rne(lo.x); t.u[1] = f32_to_bf16_rne(lo.y);
            t.u[2] = f32_to_bf16_rne(lo.z); t.u[3] = f32_to_bf16_rne(lo.w);
            t.u[4] = f32_to_bf16_rne(hi.x); t.u[5] = f32_to_bf16_rne(hi.y);
            t.u[6] = f32_to_bf16_rne(hi.z); t.u[7] = f32_to_bf16_rne(hi.w);
            afr[kc] = t.v;
        }
    }

    f32x4 acc[6];
#pragma unroll
    for (int nt = 0; nt < 6; nt++) acc[nt] = (f32x4){0.f, 0.f, 0.f, 0.f};
#pragma unroll
    for (int kc = 0; kc < 3; kc++)
#pragma unroll
        for (int nt = 0; nt < 6; nt++)
            acc[nt] = __builtin_amdgcn_mfma_f32_16x16x32_bf16(afr[kc], bfr[nt][kc], acc[nt], 0, 0, 0);

    // fused dots
    float as_[6], ad_[6];
#pragma unroll
    for (int nt = 0; nt < 6; nt++) {
        as_[nt] = avec[nt * 16 + l16];
        ad_[nt] = avec[96 + nt * 16 + l16];
    }
    float ps[4], pd[4];
#pragma unroll
    for (int r = 0; r < 4; r++) {
        float s = 0.f, d = 0.f;
#pragma unroll
        for (int nt = 0; nt < 6; nt++) {
            s = fmaf(acc[nt][r], as_[nt], s);
            d = fmaf(acc[nt][r], ad_[nt], d);
        }
        ps[r] = s; pd[r] = d;
    }
#pragma unroll
    for (int m = 1; m < 16; m <<= 1) {
#pragma unroll
        for (int r = 0; r < 4; r++) {
            ps[r] += __shfl_xor(ps[r], m);
            pd[r] += __shfl_xor(pd[r], m);
        }
    }
    {
        float psel = (l16 == 0) ? ps[0] : (l16 == 1) ? ps[1] : (l16 == 2) ? ps[2] : ps[3];
        float dsel = (l16 == 8) ? pd[0] : (l16 == 9) ? pd[1] : (l16 == 10) ? pd[2] : pd[3];
        int rs = R0 + quad * 4 + l16;
        int rd = R0 + quad * 4 + (l16 - 8);
        if (l16 < 4 && rs < NN) ssrc[rs] = psel;
        if (l16 >= 8 && l16 < 12 && rd < NN) sdst[rd] = dsel;
    }

    // store H bf16
#pragma unroll
    for (int r = 0; r < 4; r++) {
        int orow = R0 + quad * 4 + r;
        if (orow < NN) {
            unsigned short* hrow = Hout + (size_t)orow * DIM;
#pragma unroll
            for (int nt = 0; nt < 6; nt++) hrow[nt * 16 + l16] = f32_to_bf16_rne(acc[nt][r]);
        }
    }
}

// fill (blocks [0,EDGE_BLOCKS)) + layer-1 GEMM (blocks [EDGE_BLOCKS, EDGE_BLOCKS+GEMM_TILES))
__global__ __launch_bounds__(256) void fill_gemm1_kernel(const int* __restrict__ src, const int* __restrict__ dst,
                                                         int* __restrict__ cursor, int* __restrict__ dst_perm,
                                                         const float* __restrict__ x,
                                                         const unsigned short* __restrict__ Wt1,
                                                         const float* __restrict__ a1,
                                                         unsigned short* __restrict__ h1,
                                                         float* __restrict__ ssrc, float* __restrict__ sdst) {
    if (blockIdx.x < EDGE_BLOCKS) {
        int e = blockIdx.x * 256 + threadIdx.x;
        if (e < NE) {
            int s = src[e];
            int pos = atomicAdd(&cursor[s], 1);
            dst_perm[pos] = dst[e];
        }
    } else {
        gemm_tile<false>(blockIdx.x - EDGE_BLOCKS, x, Wt1, a1, h1, ssrc, sdst);
    }
}

__global__ __launch_bounds__(256) void gemm2_kernel(const unsigned short* __restrict__ h2,
                                                    const unsigned short* __restrict__ Wt2,
                                                    const float* __restrict__ a2,
                                                    unsigned short* __restrict__ h1,
                                                    float* __restrict__ ssrc, float* __restrict__ sdst) {
    gemm_tile<true>(blockIdx.x, h2, Wt2, a2, h1, ssrc, sdst);
}

// ---------------- fused CSR aggregation ----------------
// one wave per node. node/start/end forced wave-uniform (scalar loads); batch-8:
// all lanes compute the 8 edge weights redundantly on (lane&7) (1 VALU issue), shfl from 0..7;
// h-gathers use SGPR-base + lane offset (32-bit index math); wsum in lanes 0..7 only.

template <bool RELU, bool OUT_BF16>
__global__ __launch_bounds__(256) void agg_kernel(const unsigned short* __restrict__ h,
                                                  const float* __restrict__ ssrc,
                                                  const float* __restrict__ sdst,
                                                  const int* __restrict__ row_ptr,
                                                  const int* __restrict__ dst_perm,
                                                  void* __restrict__ out) {
    const int lane = threadIdx.x & 63;
    const int node = __builtin_amdgcn_readfirstlane((blockIdx.x * 256 + threadIdx.x) >> 6);
    if (node >= NN) return;
    const int start = row_ptr[node];
    const int end   = row_ptr[node + 1];
    const float ss  = ssrc[node];
    const unsigned int* __restrict__ h32 = (const unsigned int*)h;
    const bool act = lane < 48;
    const int l8 = lane & 7;
    float acc0 = 0.f, acc1 = 0.f, wsum = 0.f;

    int p = start;
    for (; p + 8 <= end; p += 8) {
        int d[8];
#pragma unroll
        for (int i = 0; i < 8; i++) d[i] = dst_perm[p + i];
        // duplicate weight compute across lane groups; shfl reads lanes 0..7
        int   dl = dst_perm[p + l8];
        float s  = ss + sdst[dl];
        float lr = s > 0.f ? s : NEG_SLOPE * s;
        float wl = __expf(-lr);
        if (lane < 8) wsum += wl;
        unsigned int u[8];
        if (act) {
#pragma unroll
            for (int i = 0; i < 8; i++) u[i] = h32[(unsigned int)d[i] * 48u + (unsigned int)lane];
        }
#pragma unroll
        for (int i = 0; i < 8; i++) {
            float w = __shfl(wl, i);
            if (act) {
                acc0 = fmaf(w, bf16lo_to_f32(u[i]), acc0);
                acc1 = fmaf(w, bf16hi_to_f32(u[i]), acc1);
            }
        }
    }
    if (p < end) {
        const int cnt = end - p;   // 1..7
        int d[8];
#pragma unroll
        for (int i = 0; i < 8; i++) d[i] = dst_perm[p + ((i < cnt) ? i : 0)];
        float wl = 0.f;
        if (l8 < cnt) {
            int   dl = dst_perm[p + l8];
            float s  = ss + sdst[dl];
            float lr = s > 0.f ? s : NEG_SLOPE * s;
            wl = __expf(-lr);
        }
        if (lane < cnt) wsum += wl;
        unsigned int u[8];
        if (act) {
#pragma unroll
            for (int i = 0; i < 8; i++) u[i] = h32[(unsigned int)d[i] * 48u + (unsigned int)lane];
        }
#pragma unroll
        for (int i = 0; i < 8; i++) {
            float w = __shfl(wl, i);   // 0 for i >= cnt
            if (act) {
                acc0 = fmaf(w, bf16lo_to_f32(u[i]), acc0);
                acc1 = fmaf(w, bf16hi_to_f32(u[i]), acc1);
            }
        }
    }

    // reduce lanes 0..7 partial wsums, broadcast to all lanes
    wsum += __shfl_xor(wsum, 1);
    wsum += __shfl_xor(wsum, 2);
    wsum += __shfl_xor(wsum, 4);
    wsum = __shfl(wsum, 0);

    float inv = 1.f / wsum;
    float r0 = acc0 * inv;
    float r1 = acc1 * inv;
    if (RELU) { r0 = fmaxf(r0, 0.f); r1 = fmaxf(r1, 0.f); }
    if (act) {
        if (OUT_BF16) {
            unsigned int pk = (unsigned int)f32_to_bf16_rne(r0) | ((unsigned int)f32_to_bf16_rne(r1) << 16);
            ((unsigned int*)out)[(size_t)node * 48 + lane] = pk;
        } else {
            ((float2*)out)[(size_t)node * 48 + lane] = make_float2(r0, r1);
        }
    }
}

// ---------------- launch ----------------

extern "C" void kernel_launch(void* const* d_in, const int* in_sizes, int n_in,
                              void* d_out, int out_size, void* d_ws, size_t ws_size,
                              hipStream_t stream) {
    (void)in_sizes; (void)n_in; (void)out_size; (void)ws_size;
    const int*   edge_index = (const int*)d_in[0];
    const float* x  = (const float*)d_in[1];
    const float* W1 = (const float*)d_in[2];
    const float* a1 = (const float*)d_in[3];
    const float* W2 = (const float*)d_in[4];
    const float* a2 = (const float*)d_in[5];
    float* out = (float*)d_out;

    const int* src = edge_index;
    const int* dst = edge_index + NE;

    char* ws = (char*)d_ws;
    size_t off = 0;
    auto alloc = [&](size_t bytes) -> void* {
        void* p = ws + off;
        off += (bytes + 255) & ~(size_t)255;
        return p;
    };
    unsigned short* h1 = (unsigned short*)alloc((size_t)NN * DIM * 2);   // gemm out (both layers)
    unsigned short* h2 = (unsigned short*)alloc((size_t)NN * DIM * 2);   // layer-1 agg out
    float* ssrc      = (float*)alloc((size_t)NN * 4);
    float* sdst      = (float*)alloc((size_t)NN * 4);
    int*   deg       = (int*)alloc((size_t)NN * 4);
    int*   row_ptr   = (int*)alloc((size_t)(NN + 1) * 4);
    int*   cursor    = (int*)alloc((size_t)NN * 4);
    int*   dst_perm  = (int*)alloc((size_t)NE * 4);
    int*   blocksum  = (int*)alloc((size_t)SCAN_BLOCKS * 4);
    unsigned short* Wt1 = (unsigned short*)alloc((size_t)DIM * DIM * 2);
    unsigned short* Wt2 = (unsigned short*)alloc((size_t)DIM * DIM * 2);

    int wave_blocks = ((NN * 64) + 255) / 256;        // 25000 (one wave per node)

    // ---- build CSR + W converts ----
    hipMemsetAsync(deg, 0, (size_t)NN * 4, stream);
    hist_conv_kernel<<<EDGE_BLOCKS + CONV_BLOCKS, 256, 0, stream>>>(src, deg, W1, Wt1, W2, Wt2);
    partial_kernel<<<SCAN_BLOCKS, 256, 0, stream>>>(deg, blocksum);
    scan_rowptr_kernel<<<SCAN_BLOCKS, 256, 0, stream>>>(deg, blocksum, row_ptr, cursor);

    // ---- fill + layer-1 GEMM (independent; one dispatch) ----
    fill_gemm1_kernel<<<EDGE_BLOCKS + GEMM_TILES, 256, 0, stream>>>(src, dst, cursor, dst_perm,
                                                                    x, Wt1, a1, h1, ssrc, sdst);
    // ---- layer 1 agg -> h2 (bf16) ----
    agg_kernel<false, true><<<wave_blocks, 256, 0, stream>>>(h1, ssrc, sdst, row_ptr, dst_perm, h2);

    // ---- layer 2 ----
    gemm2_kernel<<<GEMM_TILES, 256, 0, stream>>>(h2, Wt2, a2, h1, ssrc, sdst);
    agg_kernel<true, false><<<wave_blocks, 256, 0, stream>>>(h1, ssrc, sdst, row_ptr, dst_perm, out);
}